// Round 10
// baseline (406.969 us; speedup 1.0000x reference)
//
#include <hip/hip_runtime.h>

#define NN 50000
#define NE 800000
#define PGB 196   // precompute_G<8> blocks inside fused_pre

__device__ __forceinline__ float sigm(float v) { return 1.0f / (1.0f + __expf(-v)); }

// ===========================================================================
// Hierarchical exclusive scan over n=100000, 2048 elems/block (49 blocks).
// ===========================================================================
__global__ void scan_k1(const int* __restrict__ cnt, int n, int* __restrict__ bsum)
{
    __shared__ int s[256];
    int t = threadIdx.x;
    int base = blockIdx.x * 2048 + t * 8;
    int sum = 0;
#pragma unroll
    for (int q = 0; q < 8; ++q) { int idx = base + q; if (idx < n) sum += cnt[idx]; }
    s[t] = sum;
    __syncthreads();
#pragma unroll
    for (int d = 128; d; d >>= 1) { if (t < d) s[t] += s[t + d]; __syncthreads(); }
    if (t == 0) bsum[blockIdx.x] = s[0];
}

__global__ void scan_k2(int* __restrict__ bsum, int nblocks)
{
    __shared__ int s[512];
    int t = threadIdx.x;
    int v = (t < nblocks) ? bsum[t] : 0;
    s[t] = v;
    __syncthreads();
#pragma unroll
    for (int d = 1; d < 512; d <<= 1) {
        int a = (t >= d) ? s[t - d] : 0;
        __syncthreads();
        s[t] += a;
        __syncthreads();
    }
    if (t < nblocks) bsum[t] = s[t] - v;   // exclusive
}

__global__ void scan_k3(const int* __restrict__ cnt, int n,
                        const int* __restrict__ bsum, int* __restrict__ offset)
{
    __shared__ int s[256];
    int t = threadIdx.x;
    int base = blockIdx.x * 2048 + t * 8;
    int v[8]; int sum = 0;
#pragma unroll
    for (int q = 0; q < 8; ++q) {
        int idx = base + q;
        v[q] = (idx < n) ? cnt[idx] : 0;
        sum += v[q];
    }
    s[t] = sum;
    __syncthreads();
#pragma unroll
    for (int d = 1; d < 256; d <<= 1) {
        int a = (t >= d) ? s[t - d] : 0;
        __syncthreads();
        s[t] += a;
        __syncthreads();
    }
    int run = bsum[blockIdx.x] + ((t > 0) ? s[t - 1] : 0);
#pragma unroll
    for (int q = 0; q < 8; ++q) {
        int idx = base + q;
        if (idx <= n) offset[idx] = run;
        run += v[q];
    }
}

// ===========================================================================
// fused_pre: blocks [0,PGB) = precompute_G<8> for layer 0 (VALU-heavy,
// fills the atomic-latency bubbles of the rank blocks); blocks [PGB, PGB+3125)
// = build_ranks (1 atomic per src + per dst; ~22G atomics/s floor).
// cnt bins: [dst 0..NN) [src NN..2NN). ranks fit u16 (max degree ~45).
// ===========================================================================
__global__ __launch_bounds__(256) void fused_pre(
        const int* __restrict__ ei,
        int* __restrict__ cnt,
        unsigned short* __restrict__ rank_s,
        unsigned short* __restrict__ rank_d,
        const float* __restrict__ x,      // [NN][8]
        const float* __restrict__ eW2,    // [16][8*16]
        const float* __restrict__ eb2,    // [8*16]
        float* __restrict__ G,            // float4 [64][NN]
        float* __restrict__ xb)           // float4 [4][NN]
{
    constexpr int DIN = 8;
    __shared__ __align__(16) float w2L[16 * DIN * 16];
    __shared__ __align__(16) float b2L[DIN * 16];
    int tid = threadIdx.x;

    if (blockIdx.x < PGB) {
        for (int i = tid; i < 16 * DIN * 16; i += 256) w2L[i] = eW2[i];
        for (int i = tid; i < DIN * 16; i += 256) b2L[i] = eb2[i];
        __syncthreads();

        int n = blockIdx.x * 256 + tid;
        if (n >= NN) return;
        float xi[DIN];
#pragma unroll
        for (int i4 = 0; i4 < DIN / 4; ++i4)
            ((float4*)xi)[i4] = ((const float4*)(x + (size_t)n * DIN))[i4];

        const float4* w2v = (const float4*)w2L;
        const float4* b2v = (const float4*)b2L;
        float4* Gv  = (float4*)G;
        float4* xbv = (float4*)xb;
#pragma unroll
        for (int ob = 0; ob < 4; ++ob) {
            float4 acc = make_float4(0.f, 0.f, 0.f, 0.f);
#pragma unroll
            for (int i = 0; i < DIN; ++i) {
                float4 b = b2v[i * 4 + ob];
                acc.x += xi[i] * b.x; acc.y += xi[i] * b.y;
                acc.z += xi[i] * b.z; acc.w += xi[i] * b.w;
            }
            xbv[(size_t)ob * NN + n] = acc;
        }
#pragma unroll 1
        for (int k = 0; k < 16; ++k) {
#pragma unroll
            for (int ob = 0; ob < 4; ++ob) {
                float4 acc = make_float4(0.f, 0.f, 0.f, 0.f);
#pragma unroll
                for (int i = 0; i < DIN; ++i) {
                    float4 w = w2v[(k * DIN + i) * 4 + ob];
                    acc.x += xi[i] * w.x; acc.y += xi[i] * w.y;
                    acc.z += xi[i] * w.z; acc.w += xi[i] * w.w;
                }
                Gv[(size_t)(k * 4 + ob) * NN + n] = acc;
            }
        }
    } else {
        int e = (blockIdx.x - PGB) * 256 + tid;   // NE == 3125*256 exactly
        int s = ei[e], d = ei[NE + e];
        rank_d[e] = (unsigned short)atomicAdd(cnt + d, 1);
        rank_s[e] = (unsigned short)atomicAdd(cnt + NN + s, 1);
    }
}

// ===========================================================================
// build_perm: pack[spos] = {src, e} (8B scatter); dperm[dstpos] = spos (4B).
// Only 12 scattered bytes/edge (was 24); ea is gathered in edge_msg instead.
// ===========================================================================
__global__ void build_perm(const int* __restrict__ ei,
                           const int* __restrict__ off_all,
                           const unsigned short* __restrict__ rank_s,
                           const unsigned short* __restrict__ rank_d,
                           uint2* __restrict__ pack,
                           int* __restrict__ dperm)
{
    int e = blockIdx.x * 256 + threadIdx.x;
    int s = ei[e], d = ei[NE + e];
    int spos = off_all[NN + s] - NE + (int)rank_s[e];
    int dp   = off_all[d] + (int)rank_d[e];
    pack[spos] = make_uint2((unsigned)s, (unsigned)e);
    dperm[dp]  = spos;
}

// ===========================================================================
// Edge message, src-sorted: msg = xb[src] + sum_k h[k]*G[k][src].
// Stores msgbuf[pos] IN SRC ORDER via LDS transpose: every wave store instr
// covers full 64B lines -> no write-allocate fetch (R5 showed partial-line
// scatter fetches ~1 line per 16B store).
// ===========================================================================
__global__ __launch_bounds__(256) void edge_msg(
        const uint2* __restrict__ pack,   // [NE] {src, e} (src-sorted)
        const float* __restrict__ ea,     // [NE][4] original order
        const float* __restrict__ eW1,    // [4][16]
        const float* __restrict__ eb1,    // [16]
        const float* __restrict__ G,      // float4 [64][NN]
        const float* __restrict__ xb,     // float4 [4][NN]
        float* __restrict__ msgbuf)       // [NE][16], src-sorted rows
{
    constexpr int MROW = 260;
    __shared__ __align__(16) float4 w1t[16];
    __shared__ __align__(16) float  b1s[16];
    __shared__ float smemM[16 * MROW];
    int tid = threadIdx.x;
    if (tid < 16) {
        w1t[tid] = make_float4(eW1[tid], eW1[16 + tid], eW1[32 + tid], eW1[48 + tid]);
        b1s[tid] = eb1[tid];
    }
    __syncthreads();

    int pos = blockIdx.x * 256 + tid;
    uint2 pe = pack[pos];
    int src = (int)pe.x;
    float4 a = ((const float4*)ea)[pe.y];    // random 16B gather, L2/L3-served

    float h[16];
#pragma unroll
    for (int j = 0; j < 16; ++j) {
        float4 w = w1t[j];
        float p = b1s[j] + a.x * w.x + a.y * w.y + a.z * w.z + a.w * w.w;
        h[j] = p * sigm(p);
    }

    const float4* Gv  = (const float4*)G;
    const float4* xbv = (const float4*)xb;
    float4 acc[4];
#pragma unroll
    for (int ob = 0; ob < 4; ++ob) acc[ob] = xbv[(size_t)ob * NN + src];
#pragma unroll
    for (int k = 0; k < 16; ++k) {
        float hk = h[k];
#pragma unroll
        for (int ob = 0; ob < 4; ++ob) {
            float4 g = Gv[(size_t)(k * 4 + ob) * NN + src];
            acc[ob].x += hk * g.x; acc[ob].y += hk * g.y;
            acc[ob].z += hk * g.z; acc[ob].w += hk * g.w;
        }
    }

    // stage channel-major, then emit full-line stores (4 rows per wave instr)
#pragma unroll
    for (int ob = 0; ob < 4; ++ob) {
        smemM[(ob * 4 + 0) * MROW + tid] = acc[ob].x;
        smemM[(ob * 4 + 1) * MROW + tid] = acc[ob].y;
        smemM[(ob * 4 + 2) * MROW + tid] = acc[ob].z;
        smemM[(ob * 4 + 3) * MROW + tid] = acc[ob].w;
    }
    __syncthreads();
    int base = blockIdx.x * 256;
#pragma unroll
    for (int r = 0; r < 16; ++r) {
        int le = r * 16 + (tid >> 4);
        int ch = tid & 15;
        msgbuf[(size_t)(base + le) * 16 + ch] = smemM[ch * MROW + le];
    }
}

// ===========================================================================
// Fused gather(L0) + precompute_G<16>(L1): phase A computes x1 for the
// block's 16 nodes (dperm-indirected full-line row reads); phase B computes
// G/xb for those same nodes from LDS (w2 LDS rows padded to 20 floats:
// <=2-way banks).
// ===========================================================================
__global__ __launch_bounds__(256) void gather_pG16(
        const float* __restrict__ xin,    // [NN][8]
        const float* __restrict__ root,   // [8][16]
        const float* __restrict__ bias,   // [16]
        const int*   __restrict__ off_all,// dst CSR
        const int*   __restrict__ dperm,  // [NE] dstpos->srcpos
        const float* __restrict__ msgbuf, // [NE][16] src-sorted
        const float* __restrict__ eW2,    // [16][16*16] layer-1
        const float* __restrict__ eb2,    // [16*16]
        float* __restrict__ x1,           // [NN][16]
        float* __restrict__ G,            // float4 [64][NN]
        float* __restrict__ xb)           // float4 [4][NN]
{
    __shared__ __align__(16) float rootL[8 * 16];
    __shared__ __align__(16) float biasL[16];
    __shared__ __align__(16) float x1L[16 * 16];
    __shared__ __align__(16) float w2L[16 * 16 * 20];  // [(i*16+k)*20 + o]
    __shared__ __align__(16) float b2L[16 * 16];
    int tid = threadIdx.x;
    for (int t = tid; t < 8 * 16; t += 256) rootL[t] = root[t];
    if (tid < 16) biasL[tid] = bias[tid];
    for (int t = tid; t < 16 * 16 * 16; t += 256) {
        int k = t >> 8, rem = t & 255, i = rem >> 4, o = rem & 15;
        w2L[(i * 16 + k) * 20 + o] = eW2[t];
    }
    for (int t = tid; t < 256; t += 256) b2L[t] = eb2[t];
    __syncthreads();

    int ch = tid & 15;
    int nl = tid >> 4;
    int n  = blockIdx.x * 16 + nl;
    int s0 = off_all[n], e0 = off_all[n + 1];

    float acc = 0.f;
    for (int j = s0; j < e0; ++j) {
        int sp = dperm[j];                          // group-broadcast read
        acc += msgbuf[(size_t)sp * 16 + ch];        // one full line per group
    }
    float v = acc / fmaxf((float)(e0 - s0), 1.0f) + biasL[ch];
#pragma unroll
    for (int i = 0; i < 8; ++i)
        v += xin[(size_t)n * 8 + i] * rootL[i * 16 + ch];
    v = fmaxf(v, 0.f);
    x1[(size_t)n * 16 + ch] = v;
    x1L[nl * 16 + ch] = v;
    __syncthreads();

    // phase B: thread (nl, k=ch) computes G[k][:][n] quads and (k<4) xb
    int k = ch;
    float xs[16];
#pragma unroll
    for (int i = 0; i < 16; ++i) xs[i] = x1L[nl * 16 + i];   // broadcast
    float4* Gv = (float4*)G;
#pragma unroll
    for (int ob = 0; ob < 4; ++ob) {
        float4 a4 = make_float4(0.f, 0.f, 0.f, 0.f);
#pragma unroll
        for (int i = 0; i < 16; ++i) {
            const float4 w = *((const float4*)(w2L + (i * 16 + k) * 20) + ob);
            a4.x += xs[i] * w.x; a4.y += xs[i] * w.y;
            a4.z += xs[i] * w.z; a4.w += xs[i] * w.w;
        }
        Gv[(size_t)(k * 4 + ob) * NN + n] = a4;   // 16 full lines / wave instr
    }
    if (k < 4) {
        const float4* b2v = (const float4*)b2L;
        int ob = k;
        float4 a4 = make_float4(0.f, 0.f, 0.f, 0.f);
#pragma unroll
        for (int i = 0; i < 16; ++i) {
            float4 b = b2v[i * 4 + ob];
            a4.x += xs[i] * b.x; a4.y += xs[i] * b.y;
            a4.z += xs[i] * b.z; a4.w += xs[i] * b.w;
        }
        ((float4*)xb)[(size_t)ob * NN + n] = a4;
    }
}

// ===========================================================================
// Final gather: node update + output MLP, dperm-indirected.
// ===========================================================================
__global__ __launch_bounds__(256) void gather_final(
        const float* __restrict__ x1,     // [NN][16]
        const float* __restrict__ root,   // [16][16]
        const float* __restrict__ bias,   // [16]
        const int*   __restrict__ off_all,
        const int*   __restrict__ dperm,
        const float* __restrict__ msgbuf,
        const float* __restrict__ mW1,    // [16][16]
        const float* __restrict__ mb1,    // [16]
        const float* __restrict__ mW2,    // [16]
        const float* __restrict__ mb2,    // [1]
        float* __restrict__ out)          // [NN]
{
    __shared__ __align__(16) float rootL[256];
    __shared__ __align__(16) float biasL[16];
    __shared__ __align__(16) float w1m[256];
    __shared__ __align__(16) float b1m[16];
    __shared__ __align__(16) float w2m[16];
    __shared__ float b2m;
    int tid = threadIdx.x;
    rootL[tid] = root[tid];
    w1m[tid] = mW1[tid];
    if (tid < 16) { biasL[tid] = bias[tid]; b1m[tid] = mb1[tid]; w2m[tid] = mW2[tid]; }
    if (tid == 0) b2m = mb2[0];
    __syncthreads();

    int ch = tid & 15;
    int n  = blockIdx.x * 16 + (tid >> 4);
    int s0 = off_all[n], e0 = off_all[n + 1];

    float acc = 0.f;
    for (int j = s0; j < e0; ++j) {
        int sp = dperm[j];
        acc += msgbuf[(size_t)sp * 16 + ch];
    }
    float v = acc / fmaxf((float)(e0 - s0), 1.0f) + biasL[ch];
#pragma unroll
    for (int i = 0; i < 16; ++i)
        v += x1[(size_t)n * 16 + i] * rootL[i * 16 + ch];
    v = fmaxf(v, 0.f);

    float z = b1m[ch];
#pragma unroll
    for (int o = 0; o < 16; ++o) {
        float vo = __shfl(v, o, 16);
        z += vo * w1m[o * 16 + ch];
    }
    float ss = z * sigm(z) * w2m[ch];
#pragma unroll
    for (int off = 8; off; off >>= 1) ss += __shfl_xor(ss, off, 16);
    if (ch == 0) out[n] = sigm(ss + b2m);
}

// ===========================================================================
// Host launch
// ===========================================================================
extern "C" void kernel_launch(void* const* d_in, const int* in_sizes, int n_in,
                              void* d_out, int out_size, void* d_ws, size_t ws_size,
                              hipStream_t stream) {
    const float* x     = (const float*)d_in[0];
    const int*   ei    = (const int*)  d_in[1];
    const float* ea    = (const float*)d_in[2];
    const float* eW1_0 = (const float*)d_in[3];
    const float* eb1_0 = (const float*)d_in[4];
    const float* eW2_0 = (const float*)d_in[5];
    const float* eb2_0 = (const float*)d_in[6];
    const float* root0 = (const float*)d_in[7];
    const float* bias0 = (const float*)d_in[8];
    const float* eW1_1 = (const float*)d_in[9];
    const float* eb1_1 = (const float*)d_in[10];
    const float* eW2_1 = (const float*)d_in[11];
    const float* eb2_1 = (const float*)d_in[12];
    const float* root1 = (const float*)d_in[13];
    const float* bias1 = (const float*)d_in[14];
    const float* mW1   = (const float*)d_in[15];
    const float* mb1   = (const float*)d_in[16];
    const float* mW2   = (const float*)d_in[17];
    const float* mb2   = (const float*)d_in[18];
    float* out = (float*)d_out;

    const int EG = NE / 256;   // 3125
    const int GG = NN / 16;    // 3125
    const int SN = 2 * NN;     // 100000 scan bins
    const int SB = (SN + 2047) / 2048;  // 49

    // ---- ws layout (4B words), total ~122 MB ----
    int* W = (int*)d_ws;
    int*   off_all = W;                       // 100001 -> pad 100004
    int*   bsum    = W + 100004;              // 512
    unsigned short* rank_s = (unsigned short*)(W + 100516);  // NE u16
    unsigned short* rank_d = (unsigned short*)(W + 500516);  // NE u16
    uint2* pack    = (uint2*)(W + 900516);    // NE u64 (8B-aligned: 900516 even)
    int*   dperm   = W + 2500516;             // NE
    float* x1      = (float*)(W + 3300516);   // [NN][16]
    float* xbuf    = (float*)(W + 4100516);   // float4 [4][NN]
    float* G       = (float*)(W + 4900516);   // float4 [64][NN]
    float* msgbuf  = (float*)(W + 17700516);  // [NE][16]
    int*   cnt     = W + 17700516;            // SN ints, overlaid on msgbuf

    hipMemsetAsync(cnt, 0, SN * sizeof(int), stream);
    fused_pre<<<PGB + EG, 256, 0, stream>>>(ei, cnt, rank_s, rank_d,
                                            x, eW2_0, eb2_0, G, xbuf);
    scan_k1<<<SB, 256, 0, stream>>>(cnt, SN, bsum);
    scan_k2<<<1, 512, 0, stream>>>(bsum, SB);
    scan_k3<<<SB, 256, 0, stream>>>(cnt, SN, bsum, off_all);
    build_perm<<<EG, 256, 0, stream>>>(ei, off_all, rank_s, rank_d, pack, dperm);

    // ---- layer 0 ----
    edge_msg<<<EG, 256, 0, stream>>>(pack, ea, eW1_0, eb1_0, G, xbuf, msgbuf);
    gather_pG16<<<GG, 256, 0, stream>>>(x, root0, bias0, off_all, dperm, msgbuf,
                                        eW2_1, eb2_1, x1, G, xbuf);
    // ---- layer 1 ----
    edge_msg<<<EG, 256, 0, stream>>>(pack, ea, eW1_1, eb1_1, G, xbuf, msgbuf);
    gather_final<<<GG, 256, 0, stream>>>(x1, root1, bias1, off_all, dperm, msgbuf,
                                         mW1, mb1, mW2, mb2, out);
}

// Round 11
// 370.460 us; speedup vs baseline: 1.0986x; 1.0986x over previous
//
#include <hip/hip_runtime.h>

#define NN 50000
#define NE 800000

__device__ __forceinline__ float sigm(float v) { return 1.0f / (1.0f + __expf(-v)); }

// ===========================================================================
// Hierarchical exclusive scan over n=100000 bins, 2048 elems/block.
// ===========================================================================
__global__ void scan_k1(const int* __restrict__ cnt, int n, int* __restrict__ bsum)
{
    __shared__ int s[256];
    int t = threadIdx.x;
    int base = blockIdx.x * 2048 + t * 8;
    int sum = 0;
#pragma unroll
    for (int q = 0; q < 8; ++q) { int idx = base + q; if (idx < n) sum += cnt[idx]; }
    s[t] = sum;
    __syncthreads();
#pragma unroll
    for (int d = 128; d; d >>= 1) { if (t < d) s[t] += s[t + d]; __syncthreads(); }
    if (t == 0) bsum[blockIdx.x] = s[0];
}

__global__ void scan_k2(int* __restrict__ bsum, int nblocks)
{
    __shared__ int s[512];
    int t = threadIdx.x;
    int v = (t < nblocks) ? bsum[t] : 0;
    s[t] = v;
    __syncthreads();
#pragma unroll
    for (int d = 1; d < 512; d <<= 1) {
        int a = (t >= d) ? s[t - d] : 0;
        __syncthreads();
        s[t] += a;
        __syncthreads();
    }
    if (t < nblocks) bsum[t] = s[t] - v;   // exclusive
}

__global__ void scan_k3(const int* __restrict__ cnt, int n,
                        const int* __restrict__ bsum, int* __restrict__ offset)
{
    __shared__ int s[256];
    int t = threadIdx.x;
    int base = blockIdx.x * 2048 + t * 8;
    int v[8]; int sum = 0;
#pragma unroll
    for (int q = 0; q < 8; ++q) {
        int idx = base + q;
        v[q] = (idx < n) ? cnt[idx] : 0;
        sum += v[q];
    }
    s[t] = sum;
    __syncthreads();
#pragma unroll
    for (int d = 1; d < 256; d <<= 1) {
        int a = (t >= d) ? s[t - d] : 0;
        __syncthreads();
        s[t] += a;
        __syncthreads();
    }
    int run = bsum[blockIdx.x] + ((t > 0) ? s[t - 1] : 0);
#pragma unroll
    for (int q = 0; q < 8; ++q) {
        int idx = base + q;
        if (idx <= n) offset[idx] = run;
        run += v[q];
    }
}

// ===========================================================================
// build_ranks: standalone (R10 lesson: do NOT co-schedule streaming stores
// with this -- the ~22G atomics/s floor is coherence-pipe throughput).
// cnt bins: [dst 0..NN) [src NN..2NN). ranks fit u16 (max degree ~45).
// ===========================================================================
__global__ void build_ranks(const int* __restrict__ ei,
                            int* __restrict__ cnt,
                            unsigned short* __restrict__ rank_s,
                            unsigned short* __restrict__ rank_d)
{
    int e = blockIdx.x * 256 + threadIdx.x;   // NE == 3125*256 exactly
    int s = ei[e], d = ei[NE + e];
    rank_d[e] = (unsigned short)atomicAdd(cnt + d, 1);
    rank_s[e] = (unsigned short)atomicAdd(cnt + NN + s, 1);
}

// ===========================================================================
// build_perm: at src-sorted slot spos write pack={src,dstpos} (8B) and
// ea_s (16B). 24 scattered B/edge, once; both edge passes then read coalesced.
// ===========================================================================
__global__ void build_perm(const int* __restrict__ ei,
                           const float* __restrict__ ea,
                           const int* __restrict__ off_all,
                           const unsigned short* __restrict__ rank_s,
                           const unsigned short* __restrict__ rank_d,
                           uint2* __restrict__ pack,
                           float* __restrict__ ea_s)
{
    int e = blockIdx.x * 256 + threadIdx.x;
    int s = ei[e], d = ei[NE + e];
    int spos = off_all[NN + s] - NE + (int)rank_s[e];
    int dp   = off_all[d] + (int)rank_d[e];
    pack[spos] = make_uint2((unsigned)s, (unsigned)dp);
    ((float4*)ea_s)[spos] = ((const float4*)ea)[e];
}

// ===========================================================================
// precompute_G<8> (layer 0): G[(k*4+ob)][n] quads, xb[ob][n]; coalesced stores.
// ===========================================================================
__global__ __launch_bounds__(256) void precompute_G8(
        const float* __restrict__ x,      // [NN][8]
        const float* __restrict__ eW2,    // [16][8*16]
        const float* __restrict__ eb2,    // [8*16]
        float* __restrict__ G,            // float4 [64][NN]
        float* __restrict__ xb)           // float4 [4][NN]
{
    constexpr int DIN = 8;
    __shared__ __align__(16) float w2L[16 * DIN * 16];
    __shared__ __align__(16) float b2L[DIN * 16];
    int tid = threadIdx.x;
    for (int i = tid; i < 16 * DIN * 16; i += 256) w2L[i] = eW2[i];
    for (int i = tid; i < DIN * 16; i += 256) b2L[i] = eb2[i];
    __syncthreads();

    int n = blockIdx.x * 256 + tid;
    if (n >= NN) return;
    float xi[DIN];
#pragma unroll
    for (int i4 = 0; i4 < DIN / 4; ++i4)
        ((float4*)xi)[i4] = ((const float4*)(x + (size_t)n * DIN))[i4];

    const float4* w2v = (const float4*)w2L;
    const float4* b2v = (const float4*)b2L;
    float4* Gv  = (float4*)G;
    float4* xbv = (float4*)xb;
#pragma unroll
    for (int ob = 0; ob < 4; ++ob) {
        float4 acc = make_float4(0.f, 0.f, 0.f, 0.f);
#pragma unroll
        for (int i = 0; i < DIN; ++i) {
            float4 b = b2v[i * 4 + ob];
            acc.x += xi[i] * b.x; acc.y += xi[i] * b.y;
            acc.z += xi[i] * b.z; acc.w += xi[i] * b.w;
        }
        xbv[(size_t)ob * NN + n] = acc;
    }
#pragma unroll 1
    for (int k = 0; k < 16; ++k) {
#pragma unroll
        for (int ob = 0; ob < 4; ++ob) {
            float4 acc = make_float4(0.f, 0.f, 0.f, 0.f);
#pragma unroll
            for (int i = 0; i < DIN; ++i) {
                float4 w = w2v[(k * DIN + i) * 4 + ob];
                acc.x += xi[i] * w.x; acc.y += xi[i] * w.y;
                acc.z += xi[i] * w.z; acc.w += xi[i] * w.w;
            }
            Gv[(size_t)(k * 4 + ob) * NN + n] = acc;
        }
    }
}

// ===========================================================================
// Edge message: src-sorted coalesced reads (pack, ea_s, G via shared src),
// then R3-style LDS remap so the dst-scatter emits COMPLETE 64B rows
// (4 full lines per wave store instr -> no partial-line write-allocate).
// Gather then reads contiguous rows; no dperm stream. No atomics.
// ===========================================================================
__global__ __launch_bounds__(256) void edge_msg(
        const uint2* __restrict__ pack,   // [NE] {src, dstpos} (src-sorted)
        const float* __restrict__ ea_s,   // [NE][4] (src-sorted)
        const float* __restrict__ eW1,    // [4][16]
        const float* __restrict__ eb1,    // [16]
        const float* __restrict__ G,      // float4 [64][NN]
        const float* __restrict__ xb,     // float4 [4][NN]
        float* __restrict__ msgbuf)       // [NE][16], dst-sorted rows
{
    constexpr int MROW = 260;
    __shared__ __align__(16) float4 w1t[16];
    __shared__ __align__(16) float  b1s[16];
    __shared__ float smemM[16 * MROW];
    __shared__ int   sdp[256];
    int tid = threadIdx.x;
    if (tid < 16) {
        w1t[tid] = make_float4(eW1[tid], eW1[16 + tid], eW1[32 + tid], eW1[48 + tid]);
        b1s[tid] = eb1[tid];
    }
    __syncthreads();

    int pos = blockIdx.x * 256 + tid;
    uint2 pe = pack[pos];
    int src = (int)pe.x;
    float4 a = ((const float4*)ea_s)[pos];

    float h[16];
#pragma unroll
    for (int j = 0; j < 16; ++j) {
        float4 w = w1t[j];
        float p = b1s[j] + a.x * w.x + a.y * w.y + a.z * w.z + a.w * w.w;
        h[j] = p * sigm(p);
    }

    const float4* Gv  = (const float4*)G;
    const float4* xbv = (const float4*)xb;
    float4 acc[4];
#pragma unroll
    for (int ob = 0; ob < 4; ++ob) acc[ob] = xbv[(size_t)ob * NN + src];
#pragma unroll
    for (int k = 0; k < 16; ++k) {
        float hk = h[k];
#pragma unroll
        for (int ob = 0; ob < 4; ++ob) {
            float4 g = Gv[(size_t)(k * 4 + ob) * NN + src];
            acc[ob].x += hk * g.x; acc[ob].y += hk * g.y;
            acc[ob].z += hk * g.z; acc[ob].w += hk * g.w;
        }
    }

    // stage channel-major + dstpos, then emit full-row scattered stores
    sdp[tid] = (int)pe.y;
#pragma unroll
    for (int ob = 0; ob < 4; ++ob) {
        smemM[(ob * 4 + 0) * MROW + tid] = acc[ob].x;
        smemM[(ob * 4 + 1) * MROW + tid] = acc[ob].y;
        smemM[(ob * 4 + 2) * MROW + tid] = acc[ob].z;
        smemM[(ob * 4 + 3) * MROW + tid] = acc[ob].w;
    }
    __syncthreads();
#pragma unroll
    for (int r = 0; r < 16; ++r) {
        int le = r * 16 + (tid >> 4);
        int ch = tid & 15;
        float v = smemM[ch * MROW + le];   // 2 lanes/bank: free
        int dp = sdp[le];                  // 16-lane broadcast
        msgbuf[(size_t)dp * 16 + ch] = v;  // 4 complete 64B rows / instr
    }
}

// ===========================================================================
// Fused gather(L0) + precompute_G<16>(L1). Phase A: contiguous dst-row sums
// + node update -> x1 (also to LDS). Phase B: G/xb for the same 16 nodes.
// ===========================================================================
__global__ __launch_bounds__(256) void gather_pG16(
        const float* __restrict__ xin,    // [NN][8]
        const float* __restrict__ root,   // [8][16]
        const float* __restrict__ bias,   // [16]
        const int*   __restrict__ off_all,// dst CSR
        const float* __restrict__ msgbuf, // [NE][16] dst-sorted
        const float* __restrict__ eW2,    // [16][16*16] layer-1
        const float* __restrict__ eb2,    // [16*16]
        float* __restrict__ x1,           // [NN][16]
        float* __restrict__ G,            // float4 [64][NN]
        float* __restrict__ xb)           // float4 [4][NN]
{
    __shared__ __align__(16) float rootL[8 * 16];
    __shared__ __align__(16) float biasL[16];
    __shared__ __align__(16) float x1L[16 * 16];
    __shared__ __align__(16) float w2L[16 * 16 * 20];  // [(i*16+k)*20 + o]
    __shared__ __align__(16) float b2L[16 * 16];
    int tid = threadIdx.x;
    for (int t = tid; t < 8 * 16; t += 256) rootL[t] = root[t];
    if (tid < 16) biasL[tid] = bias[tid];
    for (int t = tid; t < 16 * 16 * 16; t += 256) {
        int k = t >> 8, rem = t & 255, i = rem >> 4, o = rem & 15;
        w2L[(i * 16 + k) * 20 + o] = eW2[t];
    }
    for (int t = tid; t < 256; t += 256) b2L[t] = eb2[t];
    __syncthreads();

    int ch = tid & 15;
    int nl = tid >> 4;
    int n  = blockIdx.x * 16 + nl;
    int s0 = off_all[n], e0 = off_all[n + 1];

    float acc = 0.f;
    for (int j = s0; j < e0; ++j)
        acc += msgbuf[(size_t)j * 16 + ch];   // contiguous full-line reads
    float v = acc / fmaxf((float)(e0 - s0), 1.0f) + biasL[ch];
#pragma unroll
    for (int i = 0; i < 8; ++i)
        v += xin[(size_t)n * 8 + i] * rootL[i * 16 + ch];
    v = fmaxf(v, 0.f);
    x1[(size_t)n * 16 + ch] = v;
    x1L[nl * 16 + ch] = v;
    __syncthreads();

    int k = ch;
    float xs[16];
#pragma unroll
    for (int i = 0; i < 16; ++i) xs[i] = x1L[nl * 16 + i];
    float4* Gv = (float4*)G;
#pragma unroll
    for (int ob = 0; ob < 4; ++ob) {
        float4 a4 = make_float4(0.f, 0.f, 0.f, 0.f);
#pragma unroll
        for (int i = 0; i < 16; ++i) {
            const float4 w = *((const float4*)(w2L + (i * 16 + k) * 20) + ob);
            a4.x += xs[i] * w.x; a4.y += xs[i] * w.y;
            a4.z += xs[i] * w.z; a4.w += xs[i] * w.w;
        }
        Gv[(size_t)(k * 4 + ob) * NN + n] = a4;
    }
    if (k < 4) {
        const float4* b2v = (const float4*)b2L;
        int ob = k;
        float4 a4 = make_float4(0.f, 0.f, 0.f, 0.f);
#pragma unroll
        for (int i = 0; i < 16; ++i) {
            float4 b = b2v[i * 4 + ob];
            a4.x += xs[i] * b.x; a4.y += xs[i] * b.y;
            a4.z += xs[i] * b.z; a4.w += xs[i] * b.w;
        }
        ((float4*)xb)[(size_t)ob * NN + n] = a4;
    }
}

// ===========================================================================
// Final gather: contiguous dst-row sums + node update + output MLP.
// ===========================================================================
__global__ __launch_bounds__(256) void gather_final(
        const float* __restrict__ x1,     // [NN][16]
        const float* __restrict__ root,   // [16][16]
        const float* __restrict__ bias,   // [16]
        const int*   __restrict__ off_all,
        const float* __restrict__ msgbuf,
        const float* __restrict__ mW1,    // [16][16]
        const float* __restrict__ mb1,    // [16]
        const float* __restrict__ mW2,    // [16]
        const float* __restrict__ mb2,    // [1]
        float* __restrict__ out)          // [NN]
{
    __shared__ __align__(16) float rootL[256];
    __shared__ __align__(16) float biasL[16];
    __shared__ __align__(16) float w1m[256];
    __shared__ __align__(16) float b1m[16];
    __shared__ __align__(16) float w2m[16];
    __shared__ float b2m;
    int tid = threadIdx.x;
    rootL[tid] = root[tid];
    w1m[tid] = mW1[tid];
    if (tid < 16) { biasL[tid] = bias[tid]; b1m[tid] = mb1[tid]; w2m[tid] = mW2[tid]; }
    if (tid == 0) b2m = mb2[0];
    __syncthreads();

    int ch = tid & 15;
    int n  = blockIdx.x * 16 + (tid >> 4);
    int s0 = off_all[n], e0 = off_all[n + 1];

    float acc = 0.f;
    for (int j = s0; j < e0; ++j)
        acc += msgbuf[(size_t)j * 16 + ch];
    float v = acc / fmaxf((float)(e0 - s0), 1.0f) + biasL[ch];
#pragma unroll
    for (int i = 0; i < 16; ++i)
        v += x1[(size_t)n * 16 + i] * rootL[i * 16 + ch];
    v = fmaxf(v, 0.f);

    float z = b1m[ch];
#pragma unroll
    for (int o = 0; o < 16; ++o) {
        float vo = __shfl(v, o, 16);
        z += vo * w1m[o * 16 + ch];
    }
    float ss = z * sigm(z) * w2m[ch];
#pragma unroll
    for (int off = 8; off; off >>= 1) ss += __shfl_xor(ss, off, 16);
    if (ch == 0) out[n] = sigm(ss + b2m);
}

// ===========================================================================
// Host launch
// ===========================================================================
extern "C" void kernel_launch(void* const* d_in, const int* in_sizes, int n_in,
                              void* d_out, int out_size, void* d_ws, size_t ws_size,
                              hipStream_t stream) {
    const float* x     = (const float*)d_in[0];
    const int*   ei    = (const int*)  d_in[1];
    const float* ea    = (const float*)d_in[2];
    const float* eW1_0 = (const float*)d_in[3];
    const float* eb1_0 = (const float*)d_in[4];
    const float* eW2_0 = (const float*)d_in[5];
    const float* eb2_0 = (const float*)d_in[6];
    const float* root0 = (const float*)d_in[7];
    const float* bias0 = (const float*)d_in[8];
    const float* eW1_1 = (const float*)d_in[9];
    const float* eb1_1 = (const float*)d_in[10];
    const float* eW2_1 = (const float*)d_in[11];
    const float* eb2_1 = (const float*)d_in[12];
    const float* root1 = (const float*)d_in[13];
    const float* bias1 = (const float*)d_in[14];
    const float* mW1   = (const float*)d_in[15];
    const float* mb1   = (const float*)d_in[16];
    const float* mW2   = (const float*)d_in[17];
    const float* mb2   = (const float*)d_in[18];
    float* out = (float*)d_out;

    const int EG = NE / 256;   // 3125
    const int GG = NN / 16;    // 3125
    const int PG = (NN + 255) / 256;    // 196
    const int SN = 2 * NN;              // 100000 bins
    const int SB = (SN + 2047) / 2048;  // 49

    // ---- ws layout (4B words), total 32,900,516 w = 131.6 MB (<134.4 proven) ----
    int* W = (int*)d_ws;
    int*   off_all = W;                       // 100001 -> pad 100004
    int*   bsum    = W + 100004;              // 512
    unsigned short* rank_s = (unsigned short*)(W + 100516);  // NE u16
    unsigned short* rank_d = (unsigned short*)(W + 500516);  // NE u16
    uint2* pack    = (uint2*)(W + 900516);    // NE {src,dstpos} (8B-aligned)
    float* ea_s    = (float*)(W + 2500516);   // [NE][4]
    float* x1      = (float*)(W + 5700516);   // [NN][16]
    float* xbuf    = (float*)(W + 6500516);   // float4 [4][NN]
    float* G       = (float*)(W + 7300516);   // float4 [64][NN]
    float* msgbuf  = (float*)(W + 20100516);  // [NE][16]
    int*   cnt     = W + 20100516;            // SN ints, overlaid on msgbuf

    hipMemsetAsync(cnt, 0, SN * sizeof(int), stream);
    build_ranks<<<EG, 256, 0, stream>>>(ei, cnt, rank_s, rank_d);
    scan_k1<<<SB, 256, 0, stream>>>(cnt, SN, bsum);
    scan_k2<<<1, 512, 0, stream>>>(bsum, SB);
    scan_k3<<<SB, 256, 0, stream>>>(cnt, SN, bsum, off_all);
    build_perm<<<EG, 256, 0, stream>>>(ei, ea, off_all, rank_s, rank_d, pack, ea_s);

    // ---- layer 0 ----
    precompute_G8<<<PG, 256, 0, stream>>>(x, eW2_0, eb2_0, G, xbuf);
    edge_msg<<<EG, 256, 0, stream>>>(pack, ea_s, eW1_0, eb1_0, G, xbuf, msgbuf);
    gather_pG16<<<GG, 256, 0, stream>>>(x, root0, bias0, off_all, msgbuf,
                                        eW2_1, eb2_1, x1, G, xbuf);
    // ---- layer 1 ----
    edge_msg<<<EG, 256, 0, stream>>>(pack, ea_s, eW1_1, eb1_1, G, xbuf, msgbuf);
    gather_final<<<GG, 256, 0, stream>>>(x1, root1, bias1, off_all, msgbuf,
                                         mW1, mb1, mW2, mb2, out);
}

// Round 12
// 332.157 us; speedup vs baseline: 1.2252x; 1.1153x over previous
//
#include <hip/hip_runtime.h>

#define NN 50000
#define NE 800000

__device__ __forceinline__ float sigm(float v) { return 1.0f / (1.0f + __expf(-v)); }

// ===========================================================================
// Hierarchical exclusive scan over n=100000 bins, 2048 elems/block.
// ===========================================================================
__global__ void scan_k1(const int* __restrict__ cnt, int n, int* __restrict__ bsum)
{
    __shared__ int s[256];
    int t = threadIdx.x;
    int base = blockIdx.x * 2048 + t * 8;
    int sum = 0;
#pragma unroll
    for (int q = 0; q < 8; ++q) { int idx = base + q; if (idx < n) sum += cnt[idx]; }
    s[t] = sum;
    __syncthreads();
#pragma unroll
    for (int d = 128; d; d >>= 1) { if (t < d) s[t] += s[t + d]; __syncthreads(); }
    if (t == 0) bsum[blockIdx.x] = s[0];
}

__global__ void scan_k2(int* __restrict__ bsum, int nblocks)
{
    __shared__ int s[512];
    int t = threadIdx.x;
    int v = (t < nblocks) ? bsum[t] : 0;
    s[t] = v;
    __syncthreads();
#pragma unroll
    for (int d = 1; d < 512; d <<= 1) {
        int a = (t >= d) ? s[t - d] : 0;
        __syncthreads();
        s[t] += a;
        __syncthreads();
    }
    if (t < nblocks) bsum[t] = s[t] - v;   // exclusive
}

__global__ void scan_k3(const int* __restrict__ cnt, int n,
                        const int* __restrict__ bsum, int* __restrict__ offset)
{
    __shared__ int s[256];
    int t = threadIdx.x;
    int base = blockIdx.x * 2048 + t * 8;
    int v[8]; int sum = 0;
#pragma unroll
    for (int q = 0; q < 8; ++q) {
        int idx = base + q;
        v[q] = (idx < n) ? cnt[idx] : 0;
        sum += v[q];
    }
    s[t] = sum;
    __syncthreads();
#pragma unroll
    for (int d = 1; d < 256; d <<= 1) {
        int a = (t >= d) ? s[t - d] : 0;
        __syncthreads();
        s[t] += a;
        __syncthreads();
    }
    int run = bsum[blockIdx.x] + ((t > 0) ? s[t - 1] : 0);
#pragma unroll
    for (int q = 0; q < 8; ++q) {
        int idx = base + q;
        if (idx <= n) offset[idx] = run;
        run += v[q];
    }
}

// ===========================================================================
// build_ranks: standalone (R10: never co-schedule with streaming stores;
// ~22G atomics/s is a coherence-pipe floor). cnt bins: [dst|src].
// ===========================================================================
__global__ void build_ranks(const int* __restrict__ ei,
                            int* __restrict__ cnt,
                            unsigned short* __restrict__ rank_s,
                            unsigned short* __restrict__ rank_d)
{
    int e = blockIdx.x * 256 + threadIdx.x;   // NE == 3125*256 exactly
    int s = ei[e], d = ei[NE + e];
    rank_d[e] = (unsigned short)atomicAdd(cnt + d, 1);
    rank_s[e] = (unsigned short)atomicAdd(cnt + NN + s, 1);
}

// ===========================================================================
// build_perm: at src-sorted slot spos write pack={src,dstpos} + ea_s.
// ===========================================================================
__global__ void build_perm(const int* __restrict__ ei,
                           const float* __restrict__ ea,
                           const int* __restrict__ off_all,
                           const unsigned short* __restrict__ rank_s,
                           const unsigned short* __restrict__ rank_d,
                           uint2* __restrict__ pack,
                           float* __restrict__ ea_s)
{
    int e = blockIdx.x * 256 + threadIdx.x;
    int s = ei[e], d = ei[NE + e];
    int spos = off_all[NN + s] - NE + (int)rank_s[e];
    int dp   = off_all[d] + (int)rank_d[e];
    pack[spos] = make_uint2((unsigned)s, (unsigned)dp);
    ((float4*)ea_s)[spos] = ((const float4*)ea)[e];
}

// ===========================================================================
// edge_fusedG<DIN>: block = all out-edges of src nodes [16b, 16b+16)
// (src-CSR aligned). Phase 1: G for these 16 nodes computed INTO LDS
// (never touches HBM -- saves ~205 MB of G round-trip vs R11).
// Phase 2: chunked edge loop; msg = xb[sl] + sum_k h[k]*G_lds[sl][k];
// LDS remap -> full-64B-row scattered stores to dst-sorted msgbuf.
// LDS: w2 staging (phase 1) unioned with scatter staging (phase 2).
// ===========================================================================
template<int DIN>
__global__ __launch_bounds__(256) void edge_fusedG(
        const float* __restrict__ xin,    // [NN][DIN]
        const uint2* __restrict__ pack,   // [NE] {src,dstpos} src-sorted
        const float* __restrict__ ea_s,   // [NE][4] src-sorted
        const float* __restrict__ eW1,    // [4][16]
        const float* __restrict__ eb1,    // [16]
        const float* __restrict__ eW2,    // [16][DIN*16]
        const float* __restrict__ eb2,    // [DIN*16]
        const int*   __restrict__ off_all,// src CSR at off_all[NN+s]
        float* __restrict__ msgbuf)       // [NE][16] dst-sorted rows
{
    constexpr int MROW = 260;
    constexpr int W2B  = DIN * 16 * 20 * 4;           // w2L bytes (phase 1)
    constexpr int SMB  = 16 * MROW * 4 + 256 * 4;     // smemM + sdp (phase 2)
    constexpr int UNIB = (W2B > SMB) ? W2B : SMB;
    __shared__ __align__(16) char uni[UNIB];
    float* w2L   = (float*)uni;                        // [(i*16+k)*20 + o]
    float* smemM = (float*)uni;                        // [16][MROW]
    int*   sdp   = (int*)(uni + 16 * MROW * 4);        // [256]
    __shared__ __align__(16) float4 G4[16 * 69];       // [sl*69 + ob*17 + k]
    __shared__ __align__(16) float4 xbL[16 * 4];       // [sl*4 + ob]
    __shared__ __align__(16) float  xL[16 * DIN];
    __shared__ __align__(16) float  b2L[DIN * 16];
    __shared__ __align__(16) float4 w1t[16];
    __shared__ __align__(16) float  b1s[16];

    int tid = threadIdx.x;
    int nb  = blockIdx.x * 16;                // first src node of block
    if (tid < 16) {
        w1t[tid] = make_float4(eW1[tid], eW1[16 + tid], eW1[32 + tid], eW1[48 + tid]);
        b1s[tid] = eb1[tid];
    }
    for (int t = tid; t < 16 * DIN * 16; t += 256) {
        int k = t / (DIN * 16);
        int rem = t - k * DIN * 16;
        int i = rem >> 4, o = rem & 15;
        w2L[(i * 16 + k) * 20 + o] = eW2[t];
    }
    for (int t = tid; t < DIN * 16; t += 256) b2L[t] = eb2[t];
    for (int t = tid; t < 16 * DIN; t += 256) xL[t] = xin[(size_t)nb * DIN + t];
    __syncthreads();

    // ---- phase 1: G + xb for 16 local nodes; thread (nl, k) ----
    {
        int nl = tid >> 4, k = tid & 15;
        const float* xrow = xL + nl * DIN;
#pragma unroll
        for (int ob = 0; ob < 4; ++ob) {
            float4 a4 = make_float4(0.f, 0.f, 0.f, 0.f);
#pragma unroll
            for (int i = 0; i < DIN; ++i) {
                const float4 w = *((const float4*)(w2L + (i * 16 + k) * 20) + ob);
                a4.x += xrow[i] * w.x; a4.y += xrow[i] * w.y;
                a4.z += xrow[i] * w.z; a4.w += xrow[i] * w.w;
            }
            G4[nl * 69 + ob * 17 + k] = a4;
        }
        if (k < 4) {
            int ob = k;
            const float4* b2v = (const float4*)b2L;
            float4 a4 = make_float4(0.f, 0.f, 0.f, 0.f);
#pragma unroll
            for (int i = 0; i < DIN; ++i) {
                float4 b = b2v[i * 4 + ob];
                a4.x += xrow[i] * b.x; a4.y += xrow[i] * b.y;
                a4.z += xrow[i] * b.z; a4.w += xrow[i] * b.w;
            }
            xbL[nl * 4 + ob] = a4;
        }
    }
    __syncthreads();   // w2L dead; uni becomes smemM/sdp

    // ---- phase 2: chunked edge loop over this block's src-CSR range ----
    int eBeg = off_all[NN + nb] - NE;
    int eEnd = off_all[NN + nb + 16] - NE;
    for (int cb = eBeg; cb < eEnd; cb += 256) {
        int pos = cb + tid;
        bool valid = pos < eEnd;
        uint2 pe = valid ? pack[pos] : make_uint2((unsigned)nb, 0u);
        float4 a = valid ? ((const float4*)ea_s)[pos] : make_float4(0.f, 0.f, 0.f, 0.f);

        float h[16];
#pragma unroll
        for (int j = 0; j < 16; ++j) {
            float4 w = w1t[j];
            float p = b1s[j] + a.x * w.x + a.y * w.y + a.z * w.z + a.w * w.w;
            h[j] = p * sigm(p);
        }

        int sl = (int)pe.x - nb;
        float4 acc[4];
#pragma unroll
        for (int ob = 0; ob < 4; ++ob) acc[ob] = xbL[sl * 4 + ob];
#pragma unroll
        for (int k = 0; k < 16; ++k) {
            float hk = h[k];
#pragma unroll
            for (int ob = 0; ob < 4; ++ob) {
                float4 g = G4[sl * 69 + ob * 17 + k];
                acc[ob].x += hk * g.x; acc[ob].y += hk * g.y;
                acc[ob].z += hk * g.z; acc[ob].w += hk * g.w;
            }
        }

        sdp[tid] = valid ? (int)pe.y : -1;
#pragma unroll
        for (int ob = 0; ob < 4; ++ob) {
            smemM[(ob * 4 + 0) * MROW + tid] = acc[ob].x;
            smemM[(ob * 4 + 1) * MROW + tid] = acc[ob].y;
            smemM[(ob * 4 + 2) * MROW + tid] = acc[ob].z;
            smemM[(ob * 4 + 3) * MROW + tid] = acc[ob].w;
        }
        __syncthreads();
#pragma unroll
        for (int r = 0; r < 16; ++r) {
            int le = r * 16 + (tid >> 4);
            int ch = tid & 15;
            int dp = sdp[le];                      // 16-lane broadcast
            float v = smemM[ch * MROW + le];       // 2 lanes/bank: free
            if (dp >= 0) msgbuf[(size_t)dp * 16 + ch] = v;  // full 64B rows
        }
        __syncthreads();
    }
}

// ===========================================================================
// gather_L0: contiguous dst-row sums + node update -> x1.
// ===========================================================================
__global__ __launch_bounds__(256) void gather_L0(
        const float* __restrict__ xin,    // [NN][8]
        const float* __restrict__ root,   // [8][16]
        const float* __restrict__ bias,   // [16]
        const int*   __restrict__ off_all,
        const float* __restrict__ msgbuf,
        float* __restrict__ x1)           // [NN][16]
{
    __shared__ __align__(16) float rootL[8 * 16];
    __shared__ __align__(16) float biasL[16];
    int tid = threadIdx.x;
    if (tid < 128) rootL[tid] = root[tid];
    if (tid < 16) biasL[tid] = bias[tid];
    __syncthreads();

    int ch = tid & 15;
    int n  = blockIdx.x * 16 + (tid >> 4);
    int s0 = off_all[n], e0 = off_all[n + 1];

    float acc = 0.f;
    for (int j = s0; j < e0; ++j)
        acc += msgbuf[(size_t)j * 16 + ch];
    float v = acc / fmaxf((float)(e0 - s0), 1.0f) + biasL[ch];
#pragma unroll
    for (int i = 0; i < 8; ++i)
        v += xin[(size_t)n * 8 + i] * rootL[i * 16 + ch];
    x1[(size_t)n * 16 + ch] = fmaxf(v, 0.f);
}

// ===========================================================================
// gather_final: contiguous dst-row sums + node update + output MLP.
// ===========================================================================
__global__ __launch_bounds__(256) void gather_final(
        const float* __restrict__ x1,     // [NN][16]
        const float* __restrict__ root,   // [16][16]
        const float* __restrict__ bias,   // [16]
        const int*   __restrict__ off_all,
        const float* __restrict__ msgbuf,
        const float* __restrict__ mW1,    // [16][16]
        const float* __restrict__ mb1,    // [16]
        const float* __restrict__ mW2,    // [16]
        const float* __restrict__ mb2,    // [1]
        float* __restrict__ out)          // [NN]
{
    __shared__ __align__(16) float rootL[256];
    __shared__ __align__(16) float biasL[16];
    __shared__ __align__(16) float w1m[256];
    __shared__ __align__(16) float b1m[16];
    __shared__ __align__(16) float w2m[16];
    __shared__ float b2m;
    int tid = threadIdx.x;
    rootL[tid] = root[tid];
    w1m[tid] = mW1[tid];
    if (tid < 16) { biasL[tid] = bias[tid]; b1m[tid] = mb1[tid]; w2m[tid] = mW2[tid]; }
    if (tid == 0) b2m = mb2[0];
    __syncthreads();

    int ch = tid & 15;
    int n  = blockIdx.x * 16 + (tid >> 4);
    int s0 = off_all[n], e0 = off_all[n + 1];

    float acc = 0.f;
    for (int j = s0; j < e0; ++j)
        acc += msgbuf[(size_t)j * 16 + ch];
    float v = acc / fmaxf((float)(e0 - s0), 1.0f) + biasL[ch];
#pragma unroll
    for (int i = 0; i < 16; ++i)
        v += x1[(size_t)n * 16 + i] * rootL[i * 16 + ch];
    v = fmaxf(v, 0.f);

    float z = b1m[ch];
#pragma unroll
    for (int o = 0; o < 16; ++o) {
        float vo = __shfl(v, o, 16);
        z += vo * w1m[o * 16 + ch];
    }
    float ss = z * sigm(z) * w2m[ch];
#pragma unroll
    for (int off = 8; off; off >>= 1) ss += __shfl_xor(ss, off, 16);
    if (ch == 0) out[n] = sigm(ss + b2m);
}

// ===========================================================================
// Host launch
// ===========================================================================
extern "C" void kernel_launch(void* const* d_in, const int* in_sizes, int n_in,
                              void* d_out, int out_size, void* d_ws, size_t ws_size,
                              hipStream_t stream) {
    const float* x     = (const float*)d_in[0];
    const int*   ei    = (const int*)  d_in[1];
    const float* ea    = (const float*)d_in[2];
    const float* eW1_0 = (const float*)d_in[3];
    const float* eb1_0 = (const float*)d_in[4];
    const float* eW2_0 = (const float*)d_in[5];
    const float* eb2_0 = (const float*)d_in[6];
    const float* root0 = (const float*)d_in[7];
    const float* bias0 = (const float*)d_in[8];
    const float* eW1_1 = (const float*)d_in[9];
    const float* eb1_1 = (const float*)d_in[10];
    const float* eW2_1 = (const float*)d_in[11];
    const float* eb2_1 = (const float*)d_in[12];
    const float* root1 = (const float*)d_in[13];
    const float* bias1 = (const float*)d_in[14];
    const float* mW1   = (const float*)d_in[15];
    const float* mb1   = (const float*)d_in[16];
    const float* mW2   = (const float*)d_in[17];
    const float* mb2   = (const float*)d_in[18];
    float* out = (float*)d_out;

    const int EG = NE / 256;   // 3125
    const int GG = NN / 16;    // 3125
    const int SN = 2 * NN;              // 100000 bins
    const int SB = (SN + 2047) / 2048;  // 49

    // ---- ws layout (4B words), total ~19.3M words = 77 MB ----
    int* W = (int*)d_ws;
    int*   off_all = W;                       // 100001 -> pad 100004
    int*   bsum    = W + 100004;              // 512
    unsigned short* rank_s = (unsigned short*)(W + 100516);  // NE u16
    unsigned short* rank_d = (unsigned short*)(W + 500516);  // NE u16
    uint2* pack    = (uint2*)(W + 900516);    // NE {src,dstpos} (8B-aligned)
    float* ea_s    = (float*)(W + 2500516);   // [NE][4]
    float* x1      = (float*)(W + 5700516);   // [NN][16]
    float* msgbuf  = (float*)(W + 6500516);   // [NE][16]
    int*   cnt     = W + 6500516;             // SN ints, overlaid on msgbuf

    hipMemsetAsync(cnt, 0, SN * sizeof(int), stream);
    build_ranks<<<EG, 256, 0, stream>>>(ei, cnt, rank_s, rank_d);
    scan_k1<<<SB, 256, 0, stream>>>(cnt, SN, bsum);
    scan_k2<<<1, 512, 0, stream>>>(bsum, SB);
    scan_k3<<<SB, 256, 0, stream>>>(cnt, SN, bsum, off_all);
    build_perm<<<EG, 256, 0, stream>>>(ei, ea, off_all, rank_s, rank_d, pack, ea_s);

    // ---- layer 0 ----
    edge_fusedG<8><<<GG, 256, 0, stream>>>(x, pack, ea_s, eW1_0, eb1_0,
                                           eW2_0, eb2_0, off_all, msgbuf);
    gather_L0<<<GG, 256, 0, stream>>>(x, root0, bias0, off_all, msgbuf, x1);

    // ---- layer 1 ----
    edge_fusedG<16><<<GG, 256, 0, stream>>>(x1, pack, ea_s, eW1_1, eb1_1,
                                            eW2_1, eb2_1, off_all, msgbuf);
    gather_final<<<GG, 256, 0, stream>>>(x1, root1, bias1, off_all, msgbuf,
                                         mW1, mb1, mW2, mb2, out);
}